// Round 3
// baseline (423.523 us; speedup 1.0000x reference)
//
#include <hip/hip_runtime.h>

// MaxUnpooling2D: B=16, H=128, W=128, C=64, S=2 -> out (16,256,256,64) f32.
//
// V6: MEASUREMENT PROBE. Kernel body is bit-identical to V5 (output-major,
// contiguous plain stores). The only change: kernel_launch enqueues it TWICE.
// The second launch writes byte-identical output (pure gather, deterministic,
// idempotent) so correctness is unaffected.
//
// Purpose: V3/V4/V5 (scattered-NT / contiguous-NT / contiguous-plain stores)
// all measured 343-352 us — zero response to large store-path changes. Either
// (A) the kernel is ~180 us with an invariant bottleneck, or (B) the kernel is
// ~70 us (near its 384 MiB roofline) and dur_us is dominated by ~280 us of
// fixed harness work (1 GiB poison fill at ~166 us + restores + gaps).
// dur(double) - dur(single) = kernel time, directly. Decision rule:
//   dur ~410-440 + top-5 all fills        -> Model B -> kernel at roofline.
//   dur ~510-550 + our kernel in top-5 x2 -> Model A -> 120 us headroom, dig.

typedef float f32x4 __attribute__((ext_vector_type(4)));
typedef int   i32x4 __attribute__((ext_vector_type(4)));

__global__ __launch_bounds__(256) void MaxUnpooling2D_13589276524630_kernel(
        const f32x4* __restrict__ upd,   // (B,H,W,C) as 4-float groups
        const i32x4* __restrict__ msk,   // (B,H,W,C) as 4-int groups
        f32x4*       __restrict__ out)   // (B,Ho,Wo,C) as 4-float groups
{
    // p indexes (b, h, x, c4): 16*128*256*16 = 8,388,608 column-pairs.
    const int p0 = blockIdx.x * (4 * 256) + threadIdx.x;

    f32x4 u[4];
    i32x4 m[4];
#pragma unroll
    for (int j = 0; j < 4; ++j) {
        const int p  = p0 + j * 256;
        const int c4 = p & 15;            // channel group 0..15
        const int x  = (p >> 4) & 255;    // output column 0..255
        const int bh = p >> 12;           // b*128 + h
        const int in_g = (bh << 11) | ((x >> 1) << 4) | c4;
        u[j] = upd[in_g];
        m[j] = msk[in_g];
    }

#pragma unroll
    for (int j = 0; j < 4; ++j) {
        const int p  = p0 + j * 256;
        const int c4 = p & 15;
        const int x  = (p >> 4) & 255;
        const int h  = (p >> 12) & 127;
        const int b  = p >> 19;

        const int fb0 = (((h << 9) | x) << 6) | (c4 << 2);
        const int fb1 = fb0 + 256 * 64;           // next output row (y=2h+1)

        f32x4 v0, v1;
        v0.x = (m[j].x == fb0    ) ? u[j].x : 0.0f;
        v0.y = (m[j].y == fb0 + 1) ? u[j].y : 0.0f;
        v0.z = (m[j].z == fb0 + 2) ? u[j].z : 0.0f;
        v0.w = (m[j].w == fb0 + 3) ? u[j].w : 0.0f;
        v1.x = (m[j].x == fb1    ) ? u[j].x : 0.0f;
        v1.y = (m[j].y == fb1 + 1) ? u[j].y : 0.0f;
        v1.z = (m[j].z == fb1 + 2) ? u[j].z : 0.0f;
        v1.w = (m[j].w == fb1 + 3) ? u[j].w : 0.0f;

        const int og0 = ((b << 22) + fb0) >> 2;
        out[og0]              = v0;
        out[og0 + (256*64/4)] = v1;
    }
}

extern "C" void kernel_launch(void* const* d_in, const int* in_sizes, int n_in,
                              void* d_out, int out_size, void* d_ws, size_t ws_size,
                              hipStream_t stream) {
    const f32x4* upd = (const f32x4*)d_in[0];
    const i32x4* msk = (const i32x4*)d_in[1];
    f32x4*       out = (f32x4*)d_out;

    const int n_pairs = 16 * 128 * 256 * 16;   // 8,388,608 (b,h,x,c4) pairs
    const int block = 256;
    const int grid = n_pairs / (block * 4);    // 8192 blocks

    // Launched TWICE on purpose: dur(double) - dur(single) isolates the
    // kernel's own duration from fixed harness work. Second launch is
    // idempotent (pure gather, identical output).
    MaxUnpooling2D_13589276524630_kernel<<<grid, block, 0, stream>>>(upd, msk, out);
    MaxUnpooling2D_13589276524630_kernel<<<grid, block, 0, stream>>>(upd, msk, out);
}

// Round 4
// 350.120 us; speedup vs baseline: 1.2097x; 1.2097x over previous
//
#include <hip/hip_runtime.h>

// MaxUnpooling2D: B=16, H=128, W=128, C=64, S=2 -> out (16,256,256,64) f32.
// Mask construction guarantees each pooled element scatters into its OWN 2x2
// window (disjoint windows), so scatter-add == gather.
//
// V7 (FINAL) = V5 restored: output-major mapping, contiguous plain stores,
// single launch. The V6 double-launch probe measured the kernel's own
// duration at ~74 us = 384 MiB / 74.4 us = 5.4 TB/s = 86% of the 6.3 TB/s
// achievable HBM ceiling (mixed read/write stream; the pure-write fill only
// reaches 79-82%). The remaining ~275 us of dur_us is fixed harness work
// (1 GiB poison fill ~165 us + restores + launch gaps), untouchable from
// kernel_launch. This is the memory-bound roofline.
//
// Structure: thread owns one output (x, c4) column-pair. It loads the single
// input float4 group (b, h=y/2, w=x/2, c4) feeding that column (lanes at x
// and x+1 duplicate the address; coalescer collapses them -> each input byte
// fetched once) and writes the two output groups (b, 2h, x, c4), (b, 2h+1,
// x, c4). Store instruction across a wave = 64 x 16 B = 1 KiB contiguous.
// Every output element written exactly once -> no memset, no atomics.

typedef float f32x4 __attribute__((ext_vector_type(4)));
typedef int   i32x4 __attribute__((ext_vector_type(4)));

__global__ __launch_bounds__(256) void MaxUnpooling2D_13589276524630_kernel(
        const f32x4* __restrict__ upd,   // (B,H,W,C) as 4-float groups
        const i32x4* __restrict__ msk,   // (B,H,W,C) as 4-int groups
        f32x4*       __restrict__ out)   // (B,Ho,Wo,C) as 4-float groups
{
    // p indexes (b, h, x, c4): 16*128*256*16 = 8,388,608 column-pairs.
    // 4 per thread, 256 threads/block -> 8192 blocks.
    const int p0 = blockIdx.x * (4 * 256) + threadIdx.x;

    f32x4 u[4];
    i32x4 m[4];
    // Issue all loads up front (deep per-wave load queue for latency hiding).
#pragma unroll
    for (int j = 0; j < 4; ++j) {
        const int p  = p0 + j * 256;
        const int c4 = p & 15;            // channel group 0..15
        const int x  = (p >> 4) & 255;    // output column 0..255
        const int bh = p >> 12;           // b*128 + h
        // input group (b,h,w=x>>1,c4): ((b*128+h)*128 + w)*16 + c4
        const int in_g = (bh << 11) | ((x >> 1) << 4) | c4;
        u[j] = upd[in_g];
        m[j] = msk[in_g];
    }

#pragma unroll
    for (int j = 0; j < 4; ++j) {
        const int p  = p0 + j * 256;
        const int c4 = p & 15;
        const int x  = (p >> 4) & 255;
        const int h  = (p >> 12) & 127;
        const int b  = p >> 19;

        // Per-batch flat float index of output element (y=2h, x, c=c4*4):
        // fb = (y*256 + x)*64 + c
        const int fb0 = (((h << 9) | x) << 6) | (c4 << 2);
        const int fb1 = fb0 + 256 * 64;           // next output row (y=2h+1)

        f32x4 v0, v1;
        v0.x = (m[j].x == fb0    ) ? u[j].x : 0.0f;
        v0.y = (m[j].y == fb0 + 1) ? u[j].y : 0.0f;
        v0.z = (m[j].z == fb0 + 2) ? u[j].z : 0.0f;
        v0.w = (m[j].w == fb0 + 3) ? u[j].w : 0.0f;
        v1.x = (m[j].x == fb1    ) ? u[j].x : 0.0f;
        v1.y = (m[j].y == fb1 + 1) ? u[j].y : 0.0f;
        v1.z = (m[j].z == fb1 + 2) ? u[j].z : 0.0f;
        v1.w = (m[j].w == fb1 + 3) ? u[j].w : 0.0f;

        // Output float4-group index: (b*2^22 + fb)/4
        const int og0 = ((b << 22) + fb0) >> 2;
        out[og0]              = v0;
        out[og0 + (256*64/4)] = v1;
    }
}

extern "C" void kernel_launch(void* const* d_in, const int* in_sizes, int n_in,
                              void* d_out, int out_size, void* d_ws, size_t ws_size,
                              hipStream_t stream) {
    const f32x4* upd = (const f32x4*)d_in[0];
    const i32x4* msk = (const i32x4*)d_in[1];
    f32x4*       out = (f32x4*)d_out;

    const int n_pairs = 16 * 128 * 256 * 16;   // 8,388,608 (b,h,x,c4) pairs
    const int block = 256;
    const int grid = n_pairs / (block * 4);    // 8192 blocks

    MaxUnpooling2D_13589276524630_kernel<<<grid, block, 0, stream>>>(upd, msk, out);
}